// Round 1
// baseline (1086.853 us; speedup 1.0000x reference)
//
#include <hip/hip_runtime.h>
#include <hip/hip_bf16.h>
#include <math.h>

#define N_NODES 100000
#define F_IN    500
#define HID     64
#define NCLS    40

// ---------------- utility ----------------
__global__ void zero_int_kernel(int* p, int n) {
    int i = blockIdx.x * 256 + threadIdx.x;
    if (i < n) p[i] = 0;
}

// ---------------- degree histogram ----------------
__global__ void hist_kernel(const int* dst, int* cnt, int E) {
    int e = blockIdx.x * 256 + threadIdx.x;
    if (e < E) atomicAdd(&cnt[dst[e]], 1);
}

// ---------------- block-level exclusive scan ----------------
__global__ void scan_block_kernel(const int* cnt, int* partial, int* blockSums, int n) {
    __shared__ int s[256];
    int tid = threadIdx.x;
    int i = blockIdx.x * 256 + tid;
    int v = (i < n) ? cnt[i] : 0;
    s[tid] = v;
    __syncthreads();
    for (int off = 1; off < 256; off <<= 1) {
        int t = (tid >= off) ? s[tid - off] : 0;
        __syncthreads();
        s[tid] += t;
        __syncthreads();
    }
    if (i < n) partial[i] = s[tid] - v;   // exclusive
    if (tid == 255) blockSums[blockIdx.x] = s[255];
}

__global__ void scan_sums_kernel(const int* blockSums, int* blockOff, int nb) {
    __shared__ int s[512];
    int tid = threadIdx.x;
    int v = (tid < nb) ? blockSums[tid] : 0;
    s[tid] = v;
    __syncthreads();
    for (int off = 1; off < 512; off <<= 1) {
        int t = (tid >= off) ? s[tid - off] : 0;
        __syncthreads();
        s[tid] += t;
        __syncthreads();
    }
    if (tid < nb) blockOff[tid] = s[tid] - v;   // exclusive
}

__global__ void finalize_scan_kernel(const int* partial, const int* blockOff, const int* cnt,
                                     int* row_ptr, int* cursor, float* dinv, int n, int E) {
    int i = blockIdx.x * 256 + threadIdx.x;
    if (i < n) {
        int rp = partial[i] + blockOff[blockIdx.x];
        row_ptr[i] = rp;
        cursor[i]  = rp;
        dinv[i] = rsqrtf((float)(cnt[i] + 1));   // +1 for self loop; always > 0
    }
    if (i == 0) row_ptr[n] = E;
}

// ---------------- CSR fill ----------------
__global__ void fill_kernel(const int* src, const int* dst, int* cursor, int* col, int E) {
    int e = blockIdx.x * 256 + threadIdx.x;
    if (e < E) {
        int d = dst[e];
        int p = atomicAdd(&cursor[d], 1);
        col[p] = src[e];
    }
}

// ---------------- GEMM1: xw = x @ W1   (N x 500) @ (500 x 64) ----------------
#define KB1 50
__global__ __launch_bounds__(256) void gemm1_kernel(const float* __restrict__ x,
                                                    const float* __restrict__ W1,
                                                    float* __restrict__ xw, int n) {
    __shared__ float As[KB1][68];   // k-major: As[k][row], pad 68 for alignment
    __shared__ float Bs[KB1][64];   // Bs[k][col]
    const int r0 = blockIdx.x * 64;
    const int t  = threadIdx.x;
    const int tr = t >> 4;   // 0..15 row group
    const int tc = t & 15;   // 0..15 col group
    float acc[4][4];
#pragma unroll
    for (int i = 0; i < 4; i++)
#pragma unroll
        for (int j = 0; j < 4; j++) acc[i][j] = 0.0f;

    for (int kb = 0; kb < F_IN; kb += KB1) {
        // load A tile: x[r0+row][kb+kk] -> As[kk][row]
        for (int idx = t; idx < 64 * KB1; idx += 256) {
            int row = idx / KB1, kk = idx % KB1;
            int gr = r0 + row;
            As[kk][row] = (gr < n) ? x[(size_t)gr * F_IN + kb + kk] : 0.0f;
        }
        // load B tile: W1[kb+kk][c] -> Bs[kk][c]
        for (int idx = t; idx < KB1 * 64; idx += 256) {
            int kk = idx >> 6, c = idx & 63;
            Bs[kk][c] = W1[(size_t)(kb + kk) * HID + c];
        }
        __syncthreads();
#pragma unroll
        for (int k = 0; k < KB1; k++) {
            float4 av = *(const float4*)&As[k][tr * 4];
            float4 bv = *(const float4*)&Bs[k][tc * 4];
            float aa[4] = {av.x, av.y, av.z, av.w};
            float bb[4] = {bv.x, bv.y, bv.z, bv.w};
#pragma unroll
            for (int i = 0; i < 4; i++)
#pragma unroll
                for (int j = 0; j < 4; j++) acc[i][j] += aa[i] * bb[j];
        }
        __syncthreads();
    }
#pragma unroll
    for (int i = 0; i < 4; i++) {
        int gr = r0 + tr * 4 + i;
        if (gr < n) {
            float4 o = make_float4(acc[i][0], acc[i][1], acc[i][2], acc[i][3]);
            *(float4*)&xw[(size_t)gr * HID + tc * 4] = o;
        }
    }
}

// ---------------- aggregation layer 1: h = relu(D^-1/2 (A+I) D^-1/2 xw + b1) ----------------
__global__ __launch_bounds__(256) void agg1_kernel(const float* __restrict__ xw,
                                                   const int* __restrict__ col,
                                                   const int* __restrict__ row_ptr,
                                                   const float* __restrict__ dinv,
                                                   const float* __restrict__ b1,
                                                   float* __restrict__ h, int n) {
    int d = blockIdx.x * 4 + (threadIdx.x >> 6);
    if (d >= n) return;
    int f = threadIdx.x & 63;
    int start = row_ptr[d], end = row_ptr[d + 1];
    float acc = 0.0f;
    for (int j = start; j < end; j++) {
        int s = col[j];
        acc += xw[(size_t)s * HID + f] * dinv[s];
    }
    float di = dinv[d];
    float v = di * acc + di * di * xw[(size_t)d * HID + f] + b1[f];
    h[(size_t)d * HID + f] = fmaxf(v, 0.0f);
}

// ---------------- GEMM2: hw = h @ W2   (N x 64) @ (64 x 40) ----------------
__global__ __launch_bounds__(256) void gemm2_kernel(const float* __restrict__ h,
                                                    const float* __restrict__ W2,
                                                    float* __restrict__ hw, int n) {
    __shared__ float Ws[HID * NCLS];
    for (int i = threadIdx.x; i < HID * NCLS; i += 256) Ws[i] = W2[i];
    __syncthreads();
    int row = blockIdx.x * 4 + (threadIdx.x >> 6);
    if (row >= n) return;
    int lane = threadIdx.x & 63;
    float hv = h[(size_t)row * HID + lane];
    int l = (lane < NCLS) ? lane : 0;
    float acc = 0.0f;
#pragma unroll
    for (int k = 0; k < HID; k++) {
        acc += __shfl(hv, k) * Ws[k * NCLS + l];
    }
    if (lane < NCLS) hw[(size_t)row * NCLS + lane] = acc;
}

// ---------------- aggregation layer 2: logits ----------------
__global__ __launch_bounds__(256) void agg2_kernel(const float* __restrict__ hw,
                                                   const int* __restrict__ col,
                                                   const int* __restrict__ row_ptr,
                                                   const float* __restrict__ dinv,
                                                   const float* __restrict__ b2,
                                                   float* __restrict__ logits, int n) {
    int d = blockIdx.x * 4 + (threadIdx.x >> 6);
    if (d >= n) return;
    int f = threadIdx.x & 63;
    if (f >= NCLS) return;
    int start = row_ptr[d], end = row_ptr[d + 1];
    float acc = 0.0f;
    for (int j = start; j < end; j++) {
        int s = col[j];
        acc += hw[(size_t)s * NCLS + f] * dinv[s];
    }
    float di = dinv[d];
    logits[(size_t)d * NCLS + f] = di * acc + di * di * hw[(size_t)d * NCLS + f] + b2[f];
}

// ---------------- log_softmax ----------------
__global__ __launch_bounds__(256) void lsm_kernel(const float* __restrict__ logits,
                                                  float* __restrict__ out, int n) {
    int d = blockIdx.x * 4 + (threadIdx.x >> 6);
    if (d >= n) return;
    int f = threadIdx.x & 63;
    float v = (f < NCLS) ? logits[(size_t)d * NCLS + f] : -INFINITY;
    float m = v;
#pragma unroll
    for (int off = 32; off >= 1; off >>= 1) m = fmaxf(m, __shfl_xor(m, off));
    float e = (f < NCLS) ? __expf(v - m) : 0.0f;
    float ssum = e;
#pragma unroll
    for (int off = 32; off >= 1; off >>= 1) ssum += __shfl_xor(ssum, off);
    if (f < NCLS) out[(size_t)d * NCLS + f] = v - m - __logf(ssum);
}

extern "C" void kernel_launch(void* const* d_in, const int* in_sizes, int n_in,
                              void* d_out, int out_size, void* d_ws, size_t ws_size,
                              hipStream_t stream) {
    const float* x  = (const float*)d_in[0];
    const int*   ei = (const int*)d_in[1];
    const float* W1 = (const float*)d_in[2];
    const float* b1 = (const float*)d_in[3];
    const float* W2 = (const float*)d_in[4];
    const float* b2 = (const float*)d_in[5];

    const int N = N_NODES;
    const int E = in_sizes[1] / 2;
    const int* src = ei;
    const int* dst = ei + E;

    // workspace layout
    float* xw      = (float*)d_ws;                  // N*64
    float* h       = xw + (size_t)N * HID;          // N*64
    float* hw      = xw;                            // reuse xw after agg1
    float* dinv    = h + (size_t)N * HID;           // N
    int*   cnt     = (int*)(dinv + N);              // N
    int*   partial = cnt + N;                       // N
    int*   row_ptr = partial + N;                   // N+1
    int*   cursor  = row_ptr + (N + 1);             // N
    int*   blockSums = cursor + N;                  // 512
    int*   blockOff  = blockSums + 512;             // 512
    int*   col     = blockOff + 512;                // E

    float* logits  = (float*)d_out + (size_t)N * NCLS;  // second output half
    float* lsm_out = (float*)d_out;                      // first output half

    const int NB_N = (N + 255) / 256;      // 391
    const int NB_E = (E + 255) / 256;      // 6250
    const int NB_W = (N + 3) / 4;          // 25000 (4 waves per 256-block)

    // 1. CSR build
    zero_int_kernel<<<NB_N, 256, 0, stream>>>(cnt, N);
    hist_kernel<<<NB_E, 256, 0, stream>>>(dst, cnt, E);
    scan_block_kernel<<<NB_N, 256, 0, stream>>>(cnt, partial, blockSums, N);
    scan_sums_kernel<<<1, 512, 0, stream>>>(blockSums, blockOff, NB_N);
    finalize_scan_kernel<<<NB_N, 256, 0, stream>>>(partial, blockOff, cnt, row_ptr, cursor, dinv, N, E);
    fill_kernel<<<NB_E, 256, 0, stream>>>(src, dst, cursor, col, E);

    // 2. layer 1
    gemm1_kernel<<<(N + 63) / 64, 256, 0, stream>>>(x, W1, xw, N);
    agg1_kernel<<<NB_W, 256, 0, stream>>>(xw, col, row_ptr, dinv, b1, h, N);

    // 3. layer 2
    gemm2_kernel<<<NB_W, 256, 0, stream>>>(h, W2, hw, N);
    agg2_kernel<<<NB_W, 256, 0, stream>>>(hw, col, row_ptr, dinv, b2, logits, N);

    // 4. log_softmax
    lsm_kernel<<<NB_W, 256, 0, stream>>>(logits, lsm_out, N);
}

// Round 2
// 740.786 us; speedup vs baseline: 1.4672x; 1.4672x over previous
//
#include <hip/hip_runtime.h>
#include <hip/hip_bf16.h>
#include <math.h>

#define N_NODES 100000
#define F_IN    500
#define HID     64
#define NCLS    40

typedef __attribute__((ext_vector_type(8))) short short8v;
typedef __attribute__((ext_vector_type(4))) float floatx4;

// ---------------- utility ----------------
__global__ void zero_int_kernel(int* p, int n) {
    int i = blockIdx.x * 256 + threadIdx.x;
    if (i < n) p[i] = 0;
}

// ---------------- degree histogram ----------------
__global__ void hist_kernel(const int* dst, int* cnt, int E) {
    int e = blockIdx.x * 256 + threadIdx.x;
    if (e < E) atomicAdd(&cnt[dst[e]], 1);
}

// ---------------- block-level exclusive scan ----------------
__global__ void scan_block_kernel(const int* cnt, int* partial, int* blockSums, int n) {
    __shared__ int s[256];
    int tid = threadIdx.x;
    int i = blockIdx.x * 256 + tid;
    int v = (i < n) ? cnt[i] : 0;
    s[tid] = v;
    __syncthreads();
    for (int off = 1; off < 256; off <<= 1) {
        int t = (tid >= off) ? s[tid - off] : 0;
        __syncthreads();
        s[tid] += t;
        __syncthreads();
    }
    if (i < n) partial[i] = s[tid] - v;   // exclusive
    if (tid == 255) blockSums[blockIdx.x] = s[255];
}

__global__ void scan_sums_kernel(const int* blockSums, int* blockOff, int nb) {
    __shared__ int s[512];
    int tid = threadIdx.x;
    int v = (tid < nb) ? blockSums[tid] : 0;
    s[tid] = v;
    __syncthreads();
    for (int off = 1; off < 512; off <<= 1) {
        int t = (tid >= off) ? s[tid - off] : 0;
        __syncthreads();
        s[tid] += t;
        __syncthreads();
    }
    if (tid < nb) blockOff[tid] = s[tid] - v;   // exclusive
}

__global__ void finalize_scan_kernel(const int* partial, const int* blockOff, const int* cnt,
                                     int* row_ptr, int* cursor, float* dinv, int n, int E) {
    int i = blockIdx.x * 256 + threadIdx.x;
    if (i < n) {
        int rp = partial[i] + blockOff[blockIdx.x];
        row_ptr[i] = rp;
        cursor[i]  = rp;
        dinv[i] = rsqrtf((float)(cnt[i] + 1));   // +1 for self loop; always > 0
    }
    if (i == 0) row_ptr[n] = E;
}

// ---------------- CSR fill ----------------
__global__ void fill_kernel(const int* src, const int* dst, int* cursor, int* col, int E) {
    int e = blockIdx.x * 256 + threadIdx.x;
    if (e < E) {
        int d = dst[e];
        int p = atomicAdd(&cursor[d], 1);
        col[p] = src[e];
    }
}

// ---------------- W1 -> bf16 transposed [64][512] (K padded 500->512 with zeros) ----
__global__ void prep_w1t_kernel(const float* __restrict__ W1, __hip_bfloat16* __restrict__ W1T) {
    int idx = blockIdx.x * 256 + threadIdx.x;   // 64*512 = 32768
    if (idx >= HID * 512) return;
    int nn = idx >> 9;
    int k  = idx & 511;
    float v = (k < F_IN) ? W1[(size_t)k * HID + nn] : 0.0f;
    W1T[idx] = __float2bfloat16(v);
}

// ---------------- GEMM1 (MFMA bf16): xw = x @ W1, M=100000 K=500(->512) N=64 ----
// Block: 256 threads = 4 waves, tile 128 rows x 64 cols. Wave: 32 rows.
__global__ __launch_bounds__(256) void gemm1_mfma(const float* __restrict__ x,
                                                  const __hip_bfloat16* __restrict__ W1T,
                                                  float* __restrict__ xw, int n) {
    // row stride 72 bf16 (144B): rotates bank start by 4/row -> uniform bank use on b128 reads
    __shared__ __align__(16) __hip_bfloat16 As[128 * 72];
    const int tid  = threadIdx.x;
    const int wave = tid >> 6;
    const int lane = tid & 63;
    const int m16  = lane & 15;
    const int q    = lane >> 4;          // 0..3
    const int r0   = blockIdx.x * 128;

    floatx4 acc[2][4];
#pragma unroll
    for (int i = 0; i < 2; i++)
#pragma unroll
        for (int j = 0; j < 4; j++) acc[i][j] = (floatx4){0.f, 0.f, 0.f, 0.f};

    const int kg    = tid & 15;           // k-group (4 floats each)
    const int rbase = tid >> 4;           // 0..15

    for (int kb = 0; kb < 512; kb += 64) {
        __syncthreads();
        // stage A tile: 128 rows x 64 k, fp32 -> bf16
        const int k4 = kb + kg * 4;
        const bool kok = (k4 < F_IN);     // F_IN%4==0 so vectors are all-or-nothing
#pragma unroll
        for (int rr = 0; rr < 8; rr++) {
            int row = rbase + rr * 16;
            int gr  = r0 + row;
            float4 v = make_float4(0.f, 0.f, 0.f, 0.f);
            if (kok && gr < n) v = *(const float4*)&x[(size_t)gr * F_IN + k4];
            __hip_bfloat16* p = &As[row * 72 + kg * 4];
            p[0] = __float2bfloat16(v.x);
            p[1] = __float2bfloat16(v.y);
            p[2] = __float2bfloat16(v.z);
            p[3] = __float2bfloat16(v.w);
        }
        __syncthreads();
        // compute: 2 k-steps of 32
#pragma unroll
        for (int kt = 0; kt < 2; kt++) {
            const int ko = kt * 32 + q * 8;
            short8v a0 = *(const short8v*)&As[(wave * 32 + m16) * 72 + ko];
            short8v a1 = *(const short8v*)&As[(wave * 32 + 16 + m16) * 72 + ko];
#pragma unroll
            for (int nt = 0; nt < 4; nt++) {
                short8v b = *(const short8v*)&W1T[(size_t)(nt * 16 + m16) * 512 + kb + ko];
                acc[0][nt] = __builtin_amdgcn_mfma_f32_16x16x32_bf16(a0, b, acc[0][nt], 0, 0, 0);
                acc[1][nt] = __builtin_amdgcn_mfma_f32_16x16x32_bf16(a1, b, acc[1][nt], 0, 0, 0);
            }
        }
    }
    // store: C layout col = lane&15, row = (lane>>4)*4 + i
#pragma unroll
    for (int mt = 0; mt < 2; mt++) {
#pragma unroll
        for (int i = 0; i < 4; i++) {
            int gr = r0 + wave * 32 + mt * 16 + q * 4 + i;
            if (gr < n) {
#pragma unroll
                for (int nt = 0; nt < 4; nt++) {
                    xw[(size_t)gr * HID + nt * 16 + m16] = acc[mt][nt][i];
                }
            }
        }
    }
}

// ------- fused agg1 + relu + gemm2: hw[d][:] = relu(norm-agg(xw)+b1) @ W2 -------
__global__ __launch_bounds__(256) void agg1_gemm2_kernel(const float* __restrict__ xw,
                                                         const int* __restrict__ col,
                                                         const int* __restrict__ row_ptr,
                                                         const float* __restrict__ dinv,
                                                         const float* __restrict__ b1,
                                                         const float* __restrict__ W2,
                                                         float* __restrict__ hw, int n) {
    __shared__ __align__(16) float Ws2[NCLS * 68];   // Ws2[l][k], pad 68 -> float4-aligned, banks spread
    for (int idx = threadIdx.x; idx < HID * NCLS; idx += 256) {
        int k = idx / NCLS, l = idx % NCLS;
        Ws2[l * 68 + k] = W2[idx];
    }
    __syncthreads();

    int d = blockIdx.x * 4 + (threadIdx.x >> 6);
    if (d >= n) return;
    int f = threadIdx.x & 63;
    int start = row_ptr[d], end = row_ptr[d + 1];
    float acc = 0.0f;
    int j = start;
    for (; j + 4 <= end; j += 4) {
        int s0 = col[j], s1 = col[j + 1], s2 = col[j + 2], s3 = col[j + 3];
        float w0 = dinv[s0], w1 = dinv[s1], w2 = dinv[s2], w3 = dinv[s3];
        acc += xw[(size_t)s0 * HID + f] * w0;
        acc += xw[(size_t)s1 * HID + f] * w1;
        acc += xw[(size_t)s2 * HID + f] * w2;
        acc += xw[(size_t)s3 * HID + f] * w3;
    }
    for (; j < end; j++) {
        int s = col[j];
        acc += xw[(size_t)s * HID + f] * dinv[s];
    }
    float di = dinv[d];
    float hval = fmaxf(di * acc + di * di * xw[(size_t)d * HID + f] + b1[f], 0.0f);

    // gemm2: each lane l<40 computes dot(h_row, W2[:,l]) via wave broadcast
    int l = (f < NCLS) ? f : 0;
    float acc2 = 0.0f;
#pragma unroll
    for (int k0 = 0; k0 < HID; k0 += 4) {
        float4 w = *(const float4*)&Ws2[l * 68 + k0];
        acc2 += __shfl(hval, k0) * w.x;
        acc2 += __shfl(hval, k0 + 1) * w.y;
        acc2 += __shfl(hval, k0 + 2) * w.z;
        acc2 += __shfl(hval, k0 + 3) * w.w;
    }
    if (f < NCLS) hw[(size_t)d * NCLS + f] = acc2;
}

// ------- fused agg2 + bias + log_softmax: writes both outputs -------
__global__ __launch_bounds__(256) void agg2_lsm_kernel(const float* __restrict__ hw,
                                                       const int* __restrict__ col,
                                                       const int* __restrict__ row_ptr,
                                                       const float* __restrict__ dinv,
                                                       const float* __restrict__ b2,
                                                       float* __restrict__ out, int n) {
    int d = blockIdx.x * 4 + (threadIdx.x >> 6);
    if (d >= n) return;
    int lane = threadIdx.x & 63;
    bool act = (lane < NCLS);
    int f = act ? lane : 0;
    int start = row_ptr[d], end = row_ptr[d + 1];
    float acc = 0.0f;
    int j = start;
    for (; j + 4 <= end; j += 4) {
        int s0 = col[j], s1 = col[j + 1], s2 = col[j + 2], s3 = col[j + 3];
        float w0 = dinv[s0], w1 = dinv[s1], w2 = dinv[s2], w3 = dinv[s3];
        acc += hw[(size_t)s0 * NCLS + f] * w0;
        acc += hw[(size_t)s1 * NCLS + f] * w1;
        acc += hw[(size_t)s2 * NCLS + f] * w2;
        acc += hw[(size_t)s3 * NCLS + f] * w3;
    }
    for (; j < end; j++) {
        int s = col[j];
        acc += hw[(size_t)s * NCLS + f] * dinv[s];
    }
    float di = dinv[d];
    float v = di * acc + di * di * hw[(size_t)d * NCLS + f] + b2[f];

    // log_softmax over 40 classes (wave-wide shuffle reduce with -inf/0 padding)
    float vv = act ? v : -INFINITY;
    float m = vv;
#pragma unroll
    for (int off = 32; off >= 1; off >>= 1) m = fmaxf(m, __shfl_xor(m, off));
    float e = act ? __expf(v - m) : 0.0f;
    float ssum = e;
#pragma unroll
    for (int off = 32; off >= 1; off >>= 1) ssum += __shfl_xor(ssum, off);
    if (act) {
        float* lsm    = out;                          // output 0: log_softmax
        float* logits = out + (size_t)N_NODES * NCLS; // output 1: logits
        logits[(size_t)d * NCLS + lane] = v;
        lsm[(size_t)d * NCLS + lane]    = v - m - __logf(ssum);
    }
}

extern "C" void kernel_launch(void* const* d_in, const int* in_sizes, int n_in,
                              void* d_out, int out_size, void* d_ws, size_t ws_size,
                              hipStream_t stream) {
    const float* x  = (const float*)d_in[0];
    const int*   ei = (const int*)d_in[1];
    const float* W1 = (const float*)d_in[2];
    const float* b1 = (const float*)d_in[3];
    const float* W2 = (const float*)d_in[4];
    const float* b2 = (const float*)d_in[5];

    const int N = N_NODES;
    const int E = in_sizes[1] / 2;
    const int* src = ei;
    const int* dst = ei + E;

    // workspace layout
    float* xw        = (float*)d_ws;                    // N*64
    float* hw        = xw + (size_t)N * HID;            // N*40
    float* dinv      = hw + (size_t)N * NCLS;           // N
    int*   cnt       = (int*)(dinv + N);                // N
    int*   partial   = cnt + N;                         // N
    int*   row_ptr   = partial + N;                     // N+1
    int*   cursor    = row_ptr + (N + 1);               // N
    int*   blockSums = cursor + N;                      // 512
    int*   blockOff  = blockSums + 512;                 // 512
    int*   col       = blockOff + 512;                  // E
    __hip_bfloat16* W1T = (__hip_bfloat16*)(col + E);   // 64*512

    const int NB_N = (N + 255) / 256;
    const int NB_E = (E + 255) / 256;
    const int NB_W = (N + 3) / 4;

    // 0. weight prep (independent)
    prep_w1t_kernel<<<(HID * 512 + 255) / 256, 256, 0, stream>>>(W1, W1T);

    // 1. CSR build
    zero_int_kernel<<<NB_N, 256, 0, stream>>>(cnt, N);
    hist_kernel<<<NB_E, 256, 0, stream>>>(dst, cnt, E);
    scan_block_kernel<<<NB_N, 256, 0, stream>>>(cnt, partial, blockSums, N);
    scan_sums_kernel<<<1, 512, 0, stream>>>(blockSums, blockOff, NB_N);
    finalize_scan_kernel<<<NB_N, 256, 0, stream>>>(partial, blockOff, cnt, row_ptr, cursor, dinv, N, E);
    fill_kernel<<<NB_E, 256, 0, stream>>>(src, dst, cursor, col, E);

    // 2. layer 1 GEMM (MFMA bf16)
    gemm1_mfma<<<(N + 127) / 128, 256, 0, stream>>>(x, W1T, xw, N);

    // 3. fused agg1 + relu + gemm2
    agg1_gemm2_kernel<<<NB_W, 256, 0, stream>>>(xw, col, row_ptr, dinv, b1, W2, hw, N);

    // 4. fused agg2 + bias + log_softmax
    agg2_lsm_kernel<<<NB_W, 256, 0, stream>>>(hw, col, row_ptr, dinv, b2, out_size ? (float*)d_out : (float*)d_out, N);
}

// Round 3
// 721.721 us; speedup vs baseline: 1.5059x; 1.0264x over previous
//
#include <hip/hip_runtime.h>
#include <hip/hip_bf16.h>
#include <math.h>

#define N_NODES 100000
#define F_IN    500
#define HID     64
#define NCLS    40

typedef __attribute__((ext_vector_type(8))) short short8v;
typedef __attribute__((ext_vector_type(4))) float floatx4;
typedef unsigned short ushort_t;

__device__ __forceinline__ float bf2f(ushort_t u) {
    union { unsigned int i; float f; } v;
    v.i = ((unsigned int)u) << 16;
    return v.f;
}
__device__ __forceinline__ ushort_t f2bf(float f) {
    __hip_bfloat16 b = __float2bfloat16(f);
    return *(ushort_t*)&b;
}

// ---------------- degree histogram ----------------
__global__ void hist_kernel(const int* dst, int* cnt, int E) {
    int e = blockIdx.x * 256 + threadIdx.x;
    if (e < E) atomicAdd(&cnt[dst[e]], 1);
}

// ---------------- block-level exclusive scan ----------------
__global__ void scan_block_kernel(const int* cnt, int* partial, int* blockSums, int n) {
    __shared__ int s[256];
    int tid = threadIdx.x;
    int i = blockIdx.x * 256 + tid;
    int v = (i < n) ? cnt[i] : 0;
    s[tid] = v;
    __syncthreads();
    for (int off = 1; off < 256; off <<= 1) {
        int t = (tid >= off) ? s[tid - off] : 0;
        __syncthreads();
        s[tid] += t;
        __syncthreads();
    }
    if (i < n) partial[i] = s[tid] - v;   // exclusive
    if (tid == 255) blockSums[blockIdx.x] = s[255];
}

__global__ void scan_sums_kernel(const int* blockSums, int* blockOff, int nb) {
    __shared__ int s[512];
    int tid = threadIdx.x;
    int v = (tid < nb) ? blockSums[tid] : 0;
    s[tid] = v;
    __syncthreads();
    for (int off = 1; off < 512; off <<= 1) {
        int t = (tid >= off) ? s[tid - off] : 0;
        __syncthreads();
        s[tid] += t;
        __syncthreads();
    }
    if (tid < nb) blockOff[tid] = s[tid] - v;   // exclusive
}

__global__ void finalize_scan_kernel(const int* partial, const int* blockOff, const int* cnt,
                                     int* row_ptr, int* cursor, float* dinv, int n, int E) {
    int i = blockIdx.x * 256 + threadIdx.x;
    if (i < n) {
        int rp = partial[i] + blockOff[blockIdx.x];
        row_ptr[i] = rp;
        cursor[i]  = rp;
        dinv[i] = rsqrtf((float)(cnt[i] + 1));   // +1 self loop; always > 0
    }
    if (i == 0) row_ptr[n] = E;
}

// ---------------- CSR fill ----------------
__global__ void fill_kernel(const int* src, const int* dst, int* cursor, int* col, int E) {
    int e = blockIdx.x * 256 + threadIdx.x;
    if (e < E) {
        int d = dst[e];
        int p = atomicAdd(&cursor[d], 1);
        col[p] = src[e];
    }
}

// ---------------- W1 -> bf16 transposed [64][512] (K padded 500->512) ----
__global__ void prep_w1t_kernel(const float* __restrict__ W1, ushort_t* __restrict__ W1T) {
    int idx = blockIdx.x * 256 + threadIdx.x;
    if (idx >= HID * 512) return;
    int nn = idx >> 9;
    int k  = idx & 511;
    float v = (k < F_IN) ? W1[(size_t)k * HID + nn] : 0.0f;
    W1T[idx] = f2bf(v);
}

// ---------------- GEMM1 (MFMA bf16): xw_s = (x @ W1) * dinv[row], stored bf16 ----
__global__ __launch_bounds__(256) void gemm1_mfma(const float* __restrict__ x,
                                                  const ushort_t* __restrict__ W1T,
                                                  const float* __restrict__ dinv,
                                                  ushort_t* __restrict__ xws, int n) {
    __shared__ __align__(16) ushort_t As[128 * 72];   // stride 72 rotates banks
    const int tid  = threadIdx.x;
    const int wave = tid >> 6;
    const int lane = tid & 63;
    const int m16  = lane & 15;
    const int q    = lane >> 4;
    const int r0   = blockIdx.x * 128;

    floatx4 acc[2][4];
#pragma unroll
    for (int i = 0; i < 2; i++)
#pragma unroll
        for (int j = 0; j < 4; j++) acc[i][j] = (floatx4){0.f, 0.f, 0.f, 0.f};

    const int kg    = tid & 15;
    const int rbase = tid >> 4;

    for (int kb = 0; kb < 512; kb += 64) {
        __syncthreads();
        const int k4 = kb + kg * 4;
        const bool kok = (k4 < F_IN);
#pragma unroll
        for (int rr = 0; rr < 8; rr++) {
            int row = rbase + rr * 16;
            int gr  = r0 + row;
            float4 v = make_float4(0.f, 0.f, 0.f, 0.f);
            if (kok && gr < n) v = *(const float4*)&x[(size_t)gr * F_IN + k4];
            ushort_t* p = &As[row * 72 + kg * 4];
            p[0] = f2bf(v.x); p[1] = f2bf(v.y); p[2] = f2bf(v.z); p[3] = f2bf(v.w);
        }
        __syncthreads();
#pragma unroll
        for (int kt = 0; kt < 2; kt++) {
            const int ko = kt * 32 + q * 8;
            short8v a0 = *(const short8v*)&As[(wave * 32 + m16) * 72 + ko];
            short8v a1 = *(const short8v*)&As[(wave * 32 + 16 + m16) * 72 + ko];
#pragma unroll
            for (int nt = 0; nt < 4; nt++) {
                short8v b = *(const short8v*)&W1T[(size_t)(nt * 16 + m16) * 512 + kb + ko];
                acc[0][nt] = __builtin_amdgcn_mfma_f32_16x16x32_bf16(a0, b, acc[0][nt], 0, 0, 0);
                acc[1][nt] = __builtin_amdgcn_mfma_f32_16x16x32_bf16(a1, b, acc[1][nt], 0, 0, 0);
            }
        }
    }
#pragma unroll
    for (int mt = 0; mt < 2; mt++) {
#pragma unroll
        for (int i = 0; i < 4; i++) {
            int gr = r0 + wave * 32 + mt * 16 + q * 4 + i;
            if (gr < n) {
                float di = dinv[gr];
#pragma unroll
                for (int nt = 0; nt < 4; nt++) {
                    xws[(size_t)gr * HID + nt * 16 + m16] = f2bf(acc[mt][nt][i] * di);
                }
            }
        }
    }
}

// ------- fused agg1 + relu + gemm2: hw_s[d] = (relu(dinv[d]*(Σ+self)+b1) @ W2) * dinv[d] -------
__global__ __launch_bounds__(256) void agg1_gemm2_kernel(const ushort_t* __restrict__ xws,
                                                         const int* __restrict__ col,
                                                         const int* __restrict__ row_ptr,
                                                         const float* __restrict__ dinv,
                                                         const float* __restrict__ b1,
                                                         const float* __restrict__ W2,
                                                         ushort_t* __restrict__ hws, int n) {
    __shared__ __align__(16) float Ws2[NCLS * 68];   // [l][k], padded
    for (int idx = threadIdx.x; idx < HID * NCLS; idx += 256) {
        int k = idx / NCLS, l = idx % NCLS;
        Ws2[l * 68 + k] = W2[idx];
    }
    __syncthreads();

    int d = blockIdx.x * 4 + (threadIdx.x >> 6);
    if (d >= n) return;
    int f = threadIdx.x & 63;
    int start = row_ptr[d], end = row_ptr[d + 1];
    float acc0 = 0.0f, acc1 = 0.0f;
    int j = start;
    for (; j + 8 <= end; j += 8) {
        int s0 = col[j],     s1 = col[j + 1], s2 = col[j + 2], s3 = col[j + 3];
        int s4 = col[j + 4], s5 = col[j + 5], s6 = col[j + 6], s7 = col[j + 7];
        acc0 += bf2f(xws[(size_t)s0 * HID + f]);
        acc1 += bf2f(xws[(size_t)s1 * HID + f]);
        acc0 += bf2f(xws[(size_t)s2 * HID + f]);
        acc1 += bf2f(xws[(size_t)s3 * HID + f]);
        acc0 += bf2f(xws[(size_t)s4 * HID + f]);
        acc1 += bf2f(xws[(size_t)s5 * HID + f]);
        acc0 += bf2f(xws[(size_t)s6 * HID + f]);
        acc1 += bf2f(xws[(size_t)s7 * HID + f]);
    }
    for (; j < end; j++) {
        acc0 += bf2f(xws[(size_t)col[j] * HID + f]);
    }
    float di = dinv[d];
    float sum = acc0 + acc1 + bf2f(xws[(size_t)d * HID + f]);   // + self (scaled row)
    float hval = fmaxf(di * sum + b1[f], 0.0f);

    // gemm2 via wave broadcast
    int l = (f < NCLS) ? f : 0;
    float acc2 = 0.0f;
#pragma unroll
    for (int k0 = 0; k0 < HID; k0 += 4) {
        float4 w = *(const float4*)&Ws2[l * 68 + k0];
        acc2 += __shfl(hval, k0) * w.x;
        acc2 += __shfl(hval, k0 + 1) * w.y;
        acc2 += __shfl(hval, k0 + 2) * w.z;
        acc2 += __shfl(hval, k0 + 3) * w.w;
    }
    if (f < NCLS) hws[(size_t)d * NCLS + f] = f2bf(acc2 * di);
}

// ------- fused agg2 + bias + log_softmax -------
__global__ __launch_bounds__(256) void agg2_lsm_kernel(const ushort_t* __restrict__ hws,
                                                       const int* __restrict__ col,
                                                       const int* __restrict__ row_ptr,
                                                       const float* __restrict__ dinv,
                                                       const float* __restrict__ b2,
                                                       float* __restrict__ out, int n) {
    int d = blockIdx.x * 4 + (threadIdx.x >> 6);
    if (d >= n) return;
    int lane = threadIdx.x & 63;
    bool act = (lane < NCLS);
    int f = act ? lane : 0;
    int start = row_ptr[d], end = row_ptr[d + 1];
    float acc0 = 0.0f, acc1 = 0.0f;
    int j = start;
    for (; j + 8 <= end; j += 8) {
        int s0 = col[j],     s1 = col[j + 1], s2 = col[j + 2], s3 = col[j + 3];
        int s4 = col[j + 4], s5 = col[j + 5], s6 = col[j + 6], s7 = col[j + 7];
        acc0 += bf2f(hws[(size_t)s0 * NCLS + f]);
        acc1 += bf2f(hws[(size_t)s1 * NCLS + f]);
        acc0 += bf2f(hws[(size_t)s2 * NCLS + f]);
        acc1 += bf2f(hws[(size_t)s3 * NCLS + f]);
        acc0 += bf2f(hws[(size_t)s4 * NCLS + f]);
        acc1 += bf2f(hws[(size_t)s5 * NCLS + f]);
        acc0 += bf2f(hws[(size_t)s6 * NCLS + f]);
        acc1 += bf2f(hws[(size_t)s7 * NCLS + f]);
    }
    for (; j < end; j++) {
        acc0 += bf2f(hws[(size_t)col[j] * NCLS + f]);
    }
    float di = dinv[d];
    float v = di * (acc0 + acc1 + bf2f(hws[(size_t)d * NCLS + f])) + b2[f];

    float vv = act ? v : -INFINITY;
    float m = vv;
#pragma unroll
    for (int off = 32; off >= 1; off >>= 1) m = fmaxf(m, __shfl_xor(m, off));
    float e = act ? __expf(v - m) : 0.0f;
    float ssum = e;
#pragma unroll
    for (int off = 32; off >= 1; off >>= 1) ssum += __shfl_xor(ssum, off);
    if (act) {
        float* lsm    = out;
        float* logits = out + (size_t)N_NODES * NCLS;
        logits[(size_t)d * NCLS + lane] = v;
        lsm[(size_t)d * NCLS + lane]    = v - m - __logf(ssum);
    }
}

extern "C" void kernel_launch(void* const* d_in, const int* in_sizes, int n_in,
                              void* d_out, int out_size, void* d_ws, size_t ws_size,
                              hipStream_t stream) {
    const float* x  = (const float*)d_in[0];
    const int*   ei = (const int*)d_in[1];
    const float* W1 = (const float*)d_in[2];
    const float* b1 = (const float*)d_in[3];
    const float* W2 = (const float*)d_in[4];
    const float* b2 = (const float*)d_in[5];

    const int N = N_NODES;
    const int E = in_sizes[1] / 2;
    const int* src = ei;
    const int* dst = ei + E;

    // workspace layout
    ushort_t* xws   = (ushort_t*)d_ws;                    // N*64 bf16
    ushort_t* hws   = xws + (size_t)N * HID;              // N*40 bf16
    ushort_t* W1T   = hws + (size_t)N * NCLS;             // 64*512 bf16
    float* dinv     = (float*)(W1T + HID * 512);          // N
    int*   cnt      = (int*)(dinv + N);                   // N
    int*   partial  = cnt + N;                            // N
    int*   row_ptr  = partial + N;                        // N+1
    int*   cursor   = row_ptr + (N + 1);                  // N
    int*   blockSums = cursor + N;                        // 512
    int*   blockOff  = blockSums + 512;                   // 512
    int*   col      = blockOff + 512;                     // E

    const int NB_N = (N + 255) / 256;
    const int NB_E = (E + 255) / 256;
    const int NB_W = (N + 3) / 4;

    // 0. weight prep + zero counts
    hipMemsetAsync(cnt, 0, (size_t)N * sizeof(int), stream);
    prep_w1t_kernel<<<(HID * 512 + 255) / 256, 256, 0, stream>>>(W1, W1T);

    // 1. CSR build (dinv comes out of finalize)
    hist_kernel<<<NB_E, 256, 0, stream>>>(dst, cnt, E);
    scan_block_kernel<<<NB_N, 256, 0, stream>>>(cnt, partial, blockSums, N);
    scan_sums_kernel<<<1, 512, 0, stream>>>(blockSums, blockOff, NB_N);
    finalize_scan_kernel<<<NB_N, 256, 0, stream>>>(partial, blockOff, cnt, row_ptr, cursor, dinv, N, E);
    fill_kernel<<<NB_E, 256, 0, stream>>>(src, dst, cursor, col, E);

    // 2. layer 1 GEMM (MFMA bf16, scaled by dinv, bf16 out)
    gemm1_mfma<<<(N + 127) / 128, 256, 0, stream>>>(x, W1T, dinv, xws, N);

    // 3. fused agg1 + relu + gemm2 (bf16 gathers, scaled rows)
    agg1_gemm2_kernel<<<NB_W, 256, 0, stream>>>(xws, col, row_ptr, dinv, b1, W2, hws, N);

    // 4. fused agg2 + bias + log_softmax
    agg2_lsm_kernel<<<NB_W, 256, 0, stream>>>(hws, col, row_ptr, dinv, b2, (float*)d_out, N);
}

// Round 4
// 648.399 us; speedup vs baseline: 1.6762x; 1.1131x over previous
//
#include <hip/hip_runtime.h>
#include <hip/hip_bf16.h>
#include <math.h>

#define N_NODES 100000
#define F_IN    500
#define HID     64
#define NCLS    40

typedef __attribute__((ext_vector_type(8))) short short8v;
typedef __attribute__((ext_vector_type(4))) float floatx4;
typedef unsigned short ushort_t;
typedef unsigned int uint_t;

__device__ __forceinline__ float bflo(uint_t u) {
    union { uint_t i; float f; } v; v.i = u << 16; return v.f;
}
__device__ __forceinline__ float bfhi(uint_t u) {
    union { uint_t i; float f; } v; v.i = u & 0xffff0000u; return v.f;
}
__device__ __forceinline__ ushort_t f2bf(float f) {
    __hip_bfloat16 b = __float2bfloat16(f);
    return *(ushort_t*)&b;
}

// ---------------- degree histogram ----------------
__global__ void hist_kernel(const int* dst, int* cnt, int E) {
    int e = blockIdx.x * 256 + threadIdx.x;
    if (e < E) atomicAdd(&cnt[dst[e]], 1);
}

// ---------------- block-level exclusive scan ----------------
__global__ void scan_block_kernel(const int* cnt, int* partial, int* blockSums, int n) {
    __shared__ int s[256];
    int tid = threadIdx.x;
    int i = blockIdx.x * 256 + tid;
    int v = (i < n) ? cnt[i] : 0;
    s[tid] = v;
    __syncthreads();
    for (int off = 1; off < 256; off <<= 1) {
        int t = (tid >= off) ? s[tid - off] : 0;
        __syncthreads();
        s[tid] += t;
        __syncthreads();
    }
    if (i < n) partial[i] = s[tid] - v;
    if (tid == 255) blockSums[blockIdx.x] = s[255];
}

__global__ void scan_sums_kernel(const int* blockSums, int* blockOff, int nb) {
    __shared__ int s[512];
    int tid = threadIdx.x;
    int v = (tid < nb) ? blockSums[tid] : 0;
    s[tid] = v;
    __syncthreads();
    for (int off = 1; off < 512; off <<= 1) {
        int t = (tid >= off) ? s[tid - off] : 0;
        __syncthreads();
        s[tid] += t;
        __syncthreads();
    }
    if (tid < nb) blockOff[tid] = s[tid] - v;
}

__global__ void finalize_scan_kernel(const int* partial, const int* blockOff, const int* cnt,
                                     int* row_ptr, int* cursor, float* dinv, int n, int E) {
    int i = blockIdx.x * 256 + threadIdx.x;
    if (i < n) {
        int rp = partial[i] + blockOff[blockIdx.x];
        row_ptr[i] = rp;
        cursor[i]  = rp;
        dinv[i] = rsqrtf((float)(cnt[i] + 1));
    }
    if (i == 0) row_ptr[n] = E;
}

// ---------------- CSR fill ----------------
__global__ void fill_kernel(const int* src, const int* dst, int* cursor, int* col, int E) {
    int e = blockIdx.x * 256 + threadIdx.x;
    if (e < E) {
        int d = dst[e];
        int p = atomicAdd(&cursor[d], 1);
        col[p] = src[e];
    }
}

// ---------------- weight prep ----------------
__global__ void prep_w1t_kernel(const float* __restrict__ W1, ushort_t* __restrict__ W1T) {
    int idx = blockIdx.x * 256 + threadIdx.x;   // 64*512
    if (idx >= HID * 512) return;
    int nn = idx >> 9;
    int k  = idx & 511;
    float v = (k < F_IN) ? W1[(size_t)k * HID + nn] : 0.0f;
    W1T[idx] = f2bf(v);
}

__global__ void prep_w2t_kernel(const float* __restrict__ W2, ushort_t* __restrict__ W2bt) {
    int idx = blockIdx.x * 256 + threadIdx.x;   // 48*64
    if (idx >= 48 * HID) return;
    int nc = idx >> 6;   // output class (padded to 48)
    int k  = idx & 63;
    float v = (nc < NCLS) ? W2[(size_t)k * NCLS + nc] : 0.0f;
    W2bt[idx] = f2bf(v);
}

// ---------------- GEMM1 (MFMA bf16): xws = (x @ W1) * dinv[row], bf16 ----
__global__ __launch_bounds__(256) void gemm1_mfma(const float* __restrict__ x,
                                                  const ushort_t* __restrict__ W1T,
                                                  const float* __restrict__ dinv,
                                                  ushort_t* __restrict__ xws, int n) {
    __shared__ __align__(16) ushort_t As[128 * 72];
    const int tid  = threadIdx.x;
    const int wave = tid >> 6;
    const int lane = tid & 63;
    const int m16  = lane & 15;
    const int q    = lane >> 4;
    const int r0   = blockIdx.x * 128;

    floatx4 acc[2][4];
#pragma unroll
    for (int i = 0; i < 2; i++)
#pragma unroll
        for (int j = 0; j < 4; j++) acc[i][j] = (floatx4){0.f, 0.f, 0.f, 0.f};

    const int kg    = tid & 15;
    const int rbase = tid >> 4;

    for (int kb = 0; kb < 512; kb += 64) {
        __syncthreads();
        const int k4 = kb + kg * 4;
        const bool kok = (k4 < F_IN);
#pragma unroll
        for (int rr = 0; rr < 8; rr++) {
            int row = rbase + rr * 16;
            int gr  = r0 + row;
            float4 v = make_float4(0.f, 0.f, 0.f, 0.f);
            if (kok && gr < n) v = *(const float4*)&x[(size_t)gr * F_IN + k4];
            ushort_t* p = &As[row * 72 + kg * 4];
            p[0] = f2bf(v.x); p[1] = f2bf(v.y); p[2] = f2bf(v.z); p[3] = f2bf(v.w);
        }
        __syncthreads();
#pragma unroll
        for (int kt = 0; kt < 2; kt++) {
            const int ko = kt * 32 + q * 8;
            short8v a0 = *(const short8v*)&As[(wave * 32 + m16) * 72 + ko];
            short8v a1 = *(const short8v*)&As[(wave * 32 + 16 + m16) * 72 + ko];
#pragma unroll
            for (int nt = 0; nt < 4; nt++) {
                short8v b = *(const short8v*)&W1T[(size_t)(nt * 16 + m16) * 512 + kb + ko];
                acc[0][nt] = __builtin_amdgcn_mfma_f32_16x16x32_bf16(a0, b, acc[0][nt], 0, 0, 0);
                acc[1][nt] = __builtin_amdgcn_mfma_f32_16x16x32_bf16(a1, b, acc[1][nt], 0, 0, 0);
            }
        }
    }
#pragma unroll
    for (int mt = 0; mt < 2; mt++) {
#pragma unroll
        for (int i = 0; i < 4; i++) {
            int gr = r0 + wave * 32 + mt * 16 + q * 4 + i;
            if (gr < n) {
                float di = dinv[gr];
#pragma unroll
                for (int nt = 0; nt < 4; nt++) {
                    xws[(size_t)gr * HID + nt * 16 + m16] = f2bf(acc[mt][nt][i] * di);
                }
            }
        }
    }
}

// ------- agg1: h[d] = relu(dinv[d]*(Σ_nbr xws[s] + xws[d]) + b1), bf16 out -------
// Wave per node. Lane (g,c): g=edge slot 0..3, c=feature quad 0..15 (uint2 = 4 bf16).
__global__ __launch_bounds__(256) void agg1_kernel(const ushort_t* __restrict__ xws,
                                                   const int* __restrict__ col,
                                                   const int* __restrict__ row_ptr,
                                                   const float* __restrict__ dinv,
                                                   const float* __restrict__ b1,
                                                   ushort_t* __restrict__ h, int n) {
    int d = blockIdx.x * 4 + (threadIdx.x >> 6);
    if (d >= n) return;
    int lane = threadIdx.x & 63;
    int g = lane >> 4, c = lane & 15;
    int start = row_ptr[d], end = row_ptr[d + 1];
    uint2 selfv = *(const uint2*)&xws[(size_t)d * HID + c * 4];
    float4 acc = make_float4(0.f, 0.f, 0.f, 0.f);
    for (int j = start; j < end; j += 16) {
#pragma unroll
        for (int t = 0; t < 4; t++) {
            int e = j + t * 4 + g;
            if (e < end) {
                int s = col[e];
                uint2 v = *(const uint2*)&xws[(size_t)s * HID + c * 4];
                acc.x += bflo(v.x); acc.y += bfhi(v.x);
                acc.z += bflo(v.y); acc.w += bfhi(v.y);
            }
        }
    }
#pragma unroll
    for (int off = 16; off <= 32; off <<= 1) {
        acc.x += __shfl_xor(acc.x, off);
        acc.y += __shfl_xor(acc.y, off);
        acc.z += __shfl_xor(acc.z, off);
        acc.w += __shfl_xor(acc.w, off);
    }
    acc.x += bflo(selfv.x); acc.y += bfhi(selfv.x);
    acc.z += bflo(selfv.y); acc.w += bfhi(selfv.y);
    if (g == 0) {
        float di = dinv[d];
        float4 b = *(const float4*)&b1[c * 4];
        uint_t p0 = (uint_t)f2bf(fmaxf(di * acc.x + b.x, 0.f)) |
                    ((uint_t)f2bf(fmaxf(di * acc.y + b.y, 0.f)) << 16);
        uint_t p1 = (uint_t)f2bf(fmaxf(di * acc.z + b.z, 0.f)) |
                    ((uint_t)f2bf(fmaxf(di * acc.w + b.w, 0.f)) << 16);
        *(uint2*)&h[(size_t)d * HID + c * 4] = make_uint2(p0, p1);
    }
}

// ------- GEMM2 (MFMA bf16): hws[d][0:40] = (h[d] @ W2)*dinv[d]; cols 40..63 = 0 -------
// Wave: 16 rows x 48 cols (3 tiles). N_NODES % 16 == 0.
__global__ __launch_bounds__(256) void gemm2_mfma(const ushort_t* __restrict__ h,
                                                  const ushort_t* __restrict__ W2bt,
                                                  const float* __restrict__ dinv,
                                                  ushort_t* __restrict__ hws, int n) {
    int wave = threadIdx.x >> 6, lane = threadIdx.x & 63;
    int m16 = lane & 15, q = lane >> 4;
    int r0 = (blockIdx.x * 4 + wave) * 16;
    if (r0 >= n) return;
    floatx4 acc[3];
#pragma unroll
    for (int nt = 0; nt < 3; nt++) acc[nt] = (floatx4){0.f, 0.f, 0.f, 0.f};
#pragma unroll
    for (int kt = 0; kt < 2; kt++) {
        short8v a = *(const short8v*)&h[(size_t)(r0 + m16) * HID + kt * 32 + q * 8];
#pragma unroll
        for (int nt = 0; nt < 3; nt++) {
            short8v b = *(const short8v*)&W2bt[(size_t)(nt * 16 + m16) * HID + kt * 32 + q * 8];
            acc[nt] = __builtin_amdgcn_mfma_f32_16x16x32_bf16(a, b, acc[nt], 0, 0, 0);
        }
    }
#pragma unroll
    for (int i = 0; i < 4; i++) {
        int gr = r0 + q * 4 + i;
        float di = dinv[gr];
#pragma unroll
        for (int nt = 0; nt < 3; nt++) {
            int cc = nt * 16 + m16;
            hws[(size_t)gr * HID + cc] = (cc < NCLS) ? f2bf(acc[nt][i] * di) : (ushort_t)0;
        }
        hws[(size_t)gr * HID + 48 + m16] = 0;
    }
}

// ------- agg2 + bias + log_softmax (hws rows are 64 bf16, 40 used) -------
__global__ __launch_bounds__(256) void agg2_lsm_kernel(const ushort_t* __restrict__ hws,
                                                       const int* __restrict__ col,
                                                       const int* __restrict__ row_ptr,
                                                       const float* __restrict__ dinv,
                                                       const float* __restrict__ b2,
                                                       float* __restrict__ out, int n) {
    int d = blockIdx.x * 4 + (threadIdx.x >> 6);
    if (d >= n) return;
    int lane = threadIdx.x & 63;
    int g = lane >> 4, c = lane & 15;
    int start = row_ptr[d], end = row_ptr[d + 1];
    uint2 selfv = *(const uint2*)&hws[(size_t)d * HID + c * 4];
    float4 acc = make_float4(0.f, 0.f, 0.f, 0.f);
    for (int j = start; j < end; j += 16) {
#pragma unroll
        for (int t = 0; t < 4; t++) {
            int e = j + t * 4 + g;
            if (e < end) {
                int s = col[e];
                uint2 v = *(const uint2*)&hws[(size_t)s * HID + c * 4];
                acc.x += bflo(v.x); acc.y += bfhi(v.x);
                acc.z += bflo(v.y); acc.w += bfhi(v.y);
            }
        }
    }
#pragma unroll
    for (int off = 16; off <= 32; off <<= 1) {
        acc.x += __shfl_xor(acc.x, off);
        acc.y += __shfl_xor(acc.y, off);
        acc.z += __shfl_xor(acc.z, off);
        acc.w += __shfl_xor(acc.w, off);
    }
    acc.x += bflo(selfv.x); acc.y += bfhi(selfv.x);
    acc.z += bflo(selfv.y); acc.w += bfhi(selfv.y);

    float di = dinv[d];
    bool act = (c < 10);   // feature quads 0..9 cover the 40 classes
    float4 b = make_float4(0.f, 0.f, 0.f, 0.f);
    if (act) b = *(const float4*)&b2[c * 4];
    float4 v;
    v.x = di * acc.x + b.x;
    v.y = di * acc.y + b.y;
    v.z = di * acc.z + b.z;
    v.w = di * acc.w + b.w;

    float m4 = act ? fmaxf(fmaxf(v.x, v.y), fmaxf(v.z, v.w)) : -INFINITY;
#pragma unroll
    for (int off = 1; off < 16; off <<= 1) m4 = fmaxf(m4, __shfl_xor(m4, off));
    float s4 = act ? (__expf(v.x - m4) + __expf(v.y - m4) + __expf(v.z - m4) + __expf(v.w - m4)) : 0.f;
#pragma unroll
    for (int off = 1; off < 16; off <<= 1) s4 += __shfl_xor(s4, off);

    if (act && g == 0) {
        float lg = __logf(s4);
        float* lsm    = out;
        float* logits = out + (size_t)N_NODES * NCLS;
        *(float4*)&logits[(size_t)d * NCLS + c * 4] = v;
        float4 o;
        o.x = v.x - m4 - lg; o.y = v.y - m4 - lg;
        o.z = v.z - m4 - lg; o.w = v.w - m4 - lg;
        *(float4*)&lsm[(size_t)d * NCLS + c * 4] = o;
    }
}

extern "C" void kernel_launch(void* const* d_in, const int* in_sizes, int n_in,
                              void* d_out, int out_size, void* d_ws, size_t ws_size,
                              hipStream_t stream) {
    const float* x  = (const float*)d_in[0];
    const int*   ei = (const int*)d_in[1];
    const float* W1 = (const float*)d_in[2];
    const float* b1 = (const float*)d_in[3];
    const float* W2 = (const float*)d_in[4];
    const float* b2 = (const float*)d_in[5];

    const int N = N_NODES;
    const int E = in_sizes[1] / 2;
    const int* src = ei;
    const int* dst = ei + E;

    // workspace layout
    ushort_t* xws  = (ushort_t*)d_ws;                  // N*64 bf16 (pre-scaled)
    ushort_t* h    = xws + (size_t)N * HID;            // N*64 bf16
    ushort_t* hws  = h + (size_t)N * HID;              // N*64 bf16 (pre-scaled, padded)
    ushort_t* W1T  = hws + (size_t)N * HID;            // 64*512
    ushort_t* W2bt = W1T + (size_t)HID * 512;          // 48*64
    float* dinv    = (float*)(W2bt + 48 * HID);        // N
    int*   cnt     = (int*)(dinv + N);                 // N
    int*   partial = cnt + N;                          // N
    int*   row_ptr = partial + N;                      // N+1
    int*   cursor  = row_ptr + (N + 1);                // N
    int*   blockSums = cursor + N;                     // 512
    int*   blockOff  = blockSums + 512;                // 512
    int*   col     = blockOff + 512;                   // E

    const int NB_N = (N + 255) / 256;
    const int NB_E = (E + 255) / 256;
    const int NB_W = (N + 3) / 4;

    hipMemsetAsync(cnt, 0, (size_t)N * sizeof(int), stream);
    prep_w1t_kernel<<<(HID * 512 + 255) / 256, 256, 0, stream>>>(W1, W1T);
    prep_w2t_kernel<<<(48 * HID + 255) / 256, 256, 0, stream>>>(W2, W2bt);

    hist_kernel<<<NB_E, 256, 0, stream>>>(dst, cnt, E);
    scan_block_kernel<<<NB_N, 256, 0, stream>>>(cnt, partial, blockSums, N);
    scan_sums_kernel<<<1, 512, 0, stream>>>(blockSums, blockOff, NB_N);
    finalize_scan_kernel<<<NB_N, 256, 0, stream>>>(partial, blockOff, cnt, row_ptr, cursor, dinv, N, E);
    fill_kernel<<<NB_E, 256, 0, stream>>>(src, dst, cursor, col, E);

    gemm1_mfma<<<(N + 127) / 128, 256, 0, stream>>>(x, W1T, dinv, xws, N);
    agg1_kernel<<<NB_W, 256, 0, stream>>>(xws, col, row_ptr, dinv, b1, h, N);
    gemm2_mfma<<<(N / 16 + 3) / 4, 256, 0, stream>>>(h, W2bt, dinv, hws, N);
    agg2_lsm_kernel<<<NB_W, 256, 0, stream>>>(hws, col, row_ptr, dinv, b2, (float*)d_out, N);
}

// Round 5
// 531.282 us; speedup vs baseline: 2.0457x; 1.2204x over previous
//
#include <hip/hip_runtime.h>
#include <hip/hip_bf16.h>
#include <math.h>

#define N_NODES 100000
#define F_IN    500
#define HID     64
#define NCLS    40
#define NBKT    ((N_NODES + 255) / 256)   // 391 coarse buckets of 256 nodes
#define STAGE_CAP 8192                     // LDS staging cap per bucket (mean 4096)

typedef __attribute__((ext_vector_type(8))) short short8v;
typedef __attribute__((ext_vector_type(4))) float floatx4;
typedef unsigned short ushort_t;
typedef unsigned int uint_t;

__device__ __forceinline__ float bflo(uint_t u) {
    union { uint_t i; float f; } v; v.i = u << 16; return v.f;
}
__device__ __forceinline__ float bfhi(uint_t u) {
    union { uint_t i; float f; } v; v.i = u & 0xffff0000u; return v.f;
}
__device__ __forceinline__ ushort_t f2bf(float f) {
    __hip_bfloat16 b = __float2bfloat16(f);
    return *(ushort_t*)&b;
}

// ============ CSR build: bucketed two-phase (no 100MB scatter) ============

// A1: coarse bucket histogram via LDS
__global__ __launch_bounds__(256) void a1_count_kernel(const int* __restrict__ dst,
                                                       int* __restrict__ bcount, int E) {
    __shared__ int c[NBKT];
    for (int i = threadIdx.x; i < NBKT; i += 256) c[i] = 0;
    __syncthreads();
    int chunk = (E + gridDim.x - 1) / gridDim.x;
    int lo = blockIdx.x * chunk;
    int hi = min(lo + chunk, E);
    for (int e = lo + threadIdx.x; e < hi; e += 256) atomicAdd(&c[dst[e] >> 8], 1);
    __syncthreads();
    for (int i = threadIdx.x; i < NBKT; i += 256)
        if (c[i]) atomicAdd(&bcount[i], c[i]);
}

// scan of bucket counts -> boff (exclusive), bcursor copy
__global__ void scan_buckets_kernel(const int* __restrict__ bcount,
                                    int* __restrict__ boff, int* __restrict__ bcursor, int E) {
    __shared__ int s[512];
    int tid = threadIdx.x;
    int v = (tid < NBKT) ? bcount[tid] : 0;
    s[tid] = v;
    __syncthreads();
    for (int off = 1; off < 512; off <<= 1) {
        int t = (tid >= off) ? s[tid - off] : 0;
        __syncthreads();
        s[tid] += t;
        __syncthreads();
    }
    if (tid < NBKT) {
        int ex = s[tid] - v;
        boff[tid] = ex;
        bcursor[tid] = ex;
    }
    if (tid == 0) boff[NBKT] = E;
}

// A2: LDS re-count, reserve contiguous runs, scatter packed words into bucket regions
__global__ __launch_bounds__(256) void a2_fill_kernel(const int* __restrict__ src,
                                                      const int* __restrict__ dst,
                                                      int* __restrict__ bcursor,
                                                      int* __restrict__ pairs, int E) {
    __shared__ int c[NBKT];
    __shared__ int base[NBKT];
    for (int i = threadIdx.x; i < NBKT; i += 256) c[i] = 0;
    __syncthreads();
    int chunk = (E + gridDim.x - 1) / gridDim.x;
    int lo = blockIdx.x * chunk;
    int hi = min(lo + chunk, E);
    for (int e = lo + threadIdx.x; e < hi; e += 256) atomicAdd(&c[dst[e] >> 8], 1);
    __syncthreads();
    for (int i = threadIdx.x; i < NBKT; i += 256) {
        int nn = c[i];
        base[i] = nn ? atomicAdd(&bcursor[i], nn) : 0;
    }
    __syncthreads();
    for (int i = threadIdx.x; i < NBKT; i += 256) c[i] = 0;
    __syncthreads();
    for (int e = lo + threadIdx.x; e < hi; e += 256) {
        int d = dst[e];
        int b = d >> 8;
        int p = base[b] + atomicAdd(&c[b], 1);
        pairs[p] = src[e] | ((d & 255) << 17);   // src < 2^17
    }
}

// B: per bucket — per-node count (LDS), scan -> row_ptr + dinv, fine scatter of col
__global__ __launch_bounds__(256) void b_fine_kernel(const int* __restrict__ pairs,
                                                     const int* __restrict__ boff,
                                                     int* __restrict__ row_ptr,
                                                     int* __restrict__ col,
                                                     float* __restrict__ dinv, int n, int E) {
    __shared__ int w[STAGE_CAP];
    __shared__ int cnt[256];
    __shared__ int scn[256];
    __shared__ int cur[256];
    int b = blockIdx.x;
    int nb0 = b << 8;
    int nodes = min(256, n - nb0);
    int g0 = boff[b], g1 = boff[b + 1];
    int size = g1 - g0;
    int stage = min(size, STAGE_CAP);
    int tid = threadIdx.x;

    for (int i = tid; i < stage; i += 256) w[i] = pairs[g0 + i];
    cnt[tid] = 0;
    __syncthreads();
    for (int i = tid; i < size; i += 256) {
        int word = (i < stage) ? w[i] : pairs[g0 + i];
        atomicAdd(&cnt[word >> 17], 1);
    }
    __syncthreads();
    int v = cnt[tid];
    scn[tid] = v;
    __syncthreads();
    for (int off = 1; off < 256; off <<= 1) {
        int t = (tid >= off) ? scn[tid - off] : 0;
        __syncthreads();
        scn[tid] += t;
        __syncthreads();
    }
    int excl = scn[tid] - v;
    cur[tid] = g0 + excl;
    if (tid < nodes) {
        row_ptr[nb0 + tid] = g0 + excl;
        dinv[nb0 + tid] = rsqrtf((float)(v + 1));
    }
    if (tid == 0 && nb0 + nodes == n) row_ptr[n] = E;
    __syncthreads();
    for (int i = tid; i < size; i += 256) {
        int word = (i < stage) ? w[i] : pairs[g0 + i];
        int pos = atomicAdd(&cur[word >> 17], 1);
        col[pos] = word & 0x1FFFF;
    }
}

// ============ weight prep ============
__global__ void prep_w1t_kernel(const float* __restrict__ W1, ushort_t* __restrict__ W1T) {
    int idx = blockIdx.x * 256 + threadIdx.x;   // 64*512
    if (idx >= HID * 512) return;
    int nn = idx >> 9;
    int k  = idx & 511;
    float v = (k < F_IN) ? W1[(size_t)k * HID + nn] : 0.0f;
    W1T[idx] = f2bf(v);
}

__global__ void prep_w2t_kernel(const float* __restrict__ W2, ushort_t* __restrict__ W2bt) {
    int idx = blockIdx.x * 256 + threadIdx.x;   // 48*64
    if (idx >= 48 * HID) return;
    int nc = idx >> 6;
    int k  = idx & 63;
    float v = (nc < NCLS) ? W2[(size_t)k * NCLS + nc] : 0.0f;
    W2bt[idx] = f2bf(v);
}

// ============ GEMM1 (MFMA bf16): xws = (x @ W1) * dinv[row], bf16 ============
__global__ __launch_bounds__(256) void gemm1_mfma(const float* __restrict__ x,
                                                  const ushort_t* __restrict__ W1T,
                                                  const float* __restrict__ dinv,
                                                  ushort_t* __restrict__ xws, int n) {
    __shared__ __align__(16) ushort_t As[128 * 72];
    const int tid  = threadIdx.x;
    const int wave = tid >> 6;
    const int lane = tid & 63;
    const int m16  = lane & 15;
    const int q    = lane >> 4;
    const int r0   = blockIdx.x * 128;

    floatx4 acc[2][4];
#pragma unroll
    for (int i = 0; i < 2; i++)
#pragma unroll
        for (int j = 0; j < 4; j++) acc[i][j] = (floatx4){0.f, 0.f, 0.f, 0.f};

    const int kg    = tid & 15;
    const int rbase = tid >> 4;

    for (int kb = 0; kb < 512; kb += 64) {
        __syncthreads();
        const int k4 = kb + kg * 4;
        const bool kok = (k4 < F_IN);
#pragma unroll
        for (int rr = 0; rr < 8; rr++) {
            int row = rbase + rr * 16;
            int gr  = r0 + row;
            float4 v = make_float4(0.f, 0.f, 0.f, 0.f);
            if (kok && gr < n) v = *(const float4*)&x[(size_t)gr * F_IN + k4];
            ushort_t* p = &As[row * 72 + kg * 4];
            p[0] = f2bf(v.x); p[1] = f2bf(v.y); p[2] = f2bf(v.z); p[3] = f2bf(v.w);
        }
        __syncthreads();
#pragma unroll
        for (int kt = 0; kt < 2; kt++) {
            const int ko = kt * 32 + q * 8;
            short8v a0 = *(const short8v*)&As[(wave * 32 + m16) * 72 + ko];
            short8v a1 = *(const short8v*)&As[(wave * 32 + 16 + m16) * 72 + ko];
#pragma unroll
            for (int nt = 0; nt < 4; nt++) {
                short8v b = *(const short8v*)&W1T[(size_t)(nt * 16 + m16) * 512 + kb + ko];
                acc[0][nt] = __builtin_amdgcn_mfma_f32_16x16x32_bf16(a0, b, acc[0][nt], 0, 0, 0);
                acc[1][nt] = __builtin_amdgcn_mfma_f32_16x16x32_bf16(a1, b, acc[1][nt], 0, 0, 0);
            }
        }
    }
#pragma unroll
    for (int mt = 0; mt < 2; mt++) {
#pragma unroll
        for (int i = 0; i < 4; i++) {
            int gr = r0 + wave * 32 + mt * 16 + q * 4 + i;
            if (gr < n) {
                float di = dinv[gr];
#pragma unroll
                for (int nt = 0; nt < 4; nt++) {
                    xws[(size_t)gr * HID + nt * 16 + m16] = f2bf(acc[mt][nt][i] * di);
                }
            }
        }
    }
}

// ============ agg1: h[d] = relu(dinv[d]*(Σ xws[s] + xws[d]) + b1), bf16 ============
__global__ __launch_bounds__(256) void agg1_kernel(const ushort_t* __restrict__ xws,
                                                   const int* __restrict__ col,
                                                   const int* __restrict__ row_ptr,
                                                   const float* __restrict__ dinv,
                                                   const float* __restrict__ b1,
                                                   ushort_t* __restrict__ h, int n) {
    int d = blockIdx.x * 4 + (threadIdx.x >> 6);
    if (d >= n) return;
    int lane = threadIdx.x & 63;
    int g = lane >> 4, c = lane & 15;
    int start = row_ptr[d], end = row_ptr[d + 1];
    uint2 selfv = *(const uint2*)&xws[(size_t)d * HID + c * 4];
    float4 acc = make_float4(0.f, 0.f, 0.f, 0.f);
    for (int j = start; j < end; j += 16) {
#pragma unroll
        for (int t = 0; t < 4; t++) {
            int e = j + t * 4 + g;
            if (e < end) {
                int s = col[e];
                uint2 v = *(const uint2*)&xws[(size_t)s * HID + c * 4];
                acc.x += bflo(v.x); acc.y += bfhi(v.x);
                acc.z += bflo(v.y); acc.w += bfhi(v.y);
            }
        }
    }
#pragma unroll
    for (int off = 16; off <= 32; off <<= 1) {
        acc.x += __shfl_xor(acc.x, off);
        acc.y += __shfl_xor(acc.y, off);
        acc.z += __shfl_xor(acc.z, off);
        acc.w += __shfl_xor(acc.w, off);
    }
    acc.x += bflo(selfv.x); acc.y += bfhi(selfv.x);
    acc.z += bflo(selfv.y); acc.w += bfhi(selfv.y);
    if (g == 0) {
        float di = dinv[d];
        float4 b = *(const float4*)&b1[c * 4];
        uint_t p0 = (uint_t)f2bf(fmaxf(di * acc.x + b.x, 0.f)) |
                    ((uint_t)f2bf(fmaxf(di * acc.y + b.y, 0.f)) << 16);
        uint_t p1 = (uint_t)f2bf(fmaxf(di * acc.z + b.z, 0.f)) |
                    ((uint_t)f2bf(fmaxf(di * acc.w + b.w, 0.f)) << 16);
        *(uint2*)&h[(size_t)d * HID + c * 4] = make_uint2(p0, p1);
    }
}

// ============ GEMM2 (MFMA bf16): hws = (h @ W2)*dinv, padded to 64 cols ============
__global__ __launch_bounds__(256) void gemm2_mfma(const ushort_t* __restrict__ h,
                                                  const ushort_t* __restrict__ W2bt,
                                                  const float* __restrict__ dinv,
                                                  ushort_t* __restrict__ hws, int n) {
    int wave = threadIdx.x >> 6, lane = threadIdx.x & 63;
    int m16 = lane & 15, q = lane >> 4;
    int r0 = (blockIdx.x * 4 + wave) * 16;
    if (r0 >= n) return;
    floatx4 acc[3];
#pragma unroll
    for (int nt = 0; nt < 3; nt++) acc[nt] = (floatx4){0.f, 0.f, 0.f, 0.f};
#pragma unroll
    for (int kt = 0; kt < 2; kt++) {
        short8v a = *(const short8v*)&h[(size_t)(r0 + m16) * HID + kt * 32 + q * 8];
#pragma unroll
        for (int nt = 0; nt < 3; nt++) {
            short8v b = *(const short8v*)&W2bt[(size_t)(nt * 16 + m16) * HID + kt * 32 + q * 8];
            acc[nt] = __builtin_amdgcn_mfma_f32_16x16x32_bf16(a, b, acc[nt], 0, 0, 0);
        }
    }
#pragma unroll
    for (int i = 0; i < 4; i++) {
        int gr = r0 + q * 4 + i;
        float di = dinv[gr];
#pragma unroll
        for (int nt = 0; nt < 3; nt++) {
            int cc = nt * 16 + m16;
            hws[(size_t)gr * HID + cc] = (cc < NCLS) ? f2bf(acc[nt][i] * di) : (ushort_t)0;
        }
        hws[(size_t)gr * HID + 48 + m16] = 0;
    }
}

// ============ agg2 + bias + log_softmax ============
__global__ __launch_bounds__(256) void agg2_lsm_kernel(const ushort_t* __restrict__ hws,
                                                       const int* __restrict__ col,
                                                       const int* __restrict__ row_ptr,
                                                       const float* __restrict__ dinv,
                                                       const float* __restrict__ b2,
                                                       float* __restrict__ out, int n) {
    int d = blockIdx.x * 4 + (threadIdx.x >> 6);
    if (d >= n) return;
    int lane = threadIdx.x & 63;
    int g = lane >> 4, c = lane & 15;
    int start = row_ptr[d], end = row_ptr[d + 1];
    uint2 selfv = *(const uint2*)&hws[(size_t)d * HID + c * 4];
    float4 acc = make_float4(0.f, 0.f, 0.f, 0.f);
    for (int j = start; j < end; j += 16) {
#pragma unroll
        for (int t = 0; t < 4; t++) {
            int e = j + t * 4 + g;
            if (e < end) {
                int s = col[e];
                uint2 v = *(const uint2*)&hws[(size_t)s * HID + c * 4];
                acc.x += bflo(v.x); acc.y += bfhi(v.x);
                acc.z += bflo(v.y); acc.w += bfhi(v.y);
            }
        }
    }
#pragma unroll
    for (int off = 16; off <= 32; off <<= 1) {
        acc.x += __shfl_xor(acc.x, off);
        acc.y += __shfl_xor(acc.y, off);
        acc.z += __shfl_xor(acc.z, off);
        acc.w += __shfl_xor(acc.w, off);
    }
    acc.x += bflo(selfv.x); acc.y += bfhi(selfv.x);
    acc.z += bflo(selfv.y); acc.w += bfhi(selfv.y);

    float di = dinv[d];
    bool act = (c < 10);
    float4 b = make_float4(0.f, 0.f, 0.f, 0.f);
    if (act) b = *(const float4*)&b2[c * 4];
    float4 v;
    v.x = di * acc.x + b.x;
    v.y = di * acc.y + b.y;
    v.z = di * acc.z + b.z;
    v.w = di * acc.w + b.w;

    float m4 = act ? fmaxf(fmaxf(v.x, v.y), fmaxf(v.z, v.w)) : -INFINITY;
#pragma unroll
    for (int off = 1; off < 16; off <<= 1) m4 = fmaxf(m4, __shfl_xor(m4, off));
    float s4 = act ? (__expf(v.x - m4) + __expf(v.y - m4) + __expf(v.z - m4) + __expf(v.w - m4)) : 0.f;
#pragma unroll
    for (int off = 1; off < 16; off <<= 1) s4 += __shfl_xor(s4, off);

    if (act && g == 0) {
        float lg = __logf(s4);
        float* lsm    = out;
        float* logits = out + (size_t)N_NODES * NCLS;
        *(float4*)&logits[(size_t)d * NCLS + c * 4] = v;
        float4 o;
        o.x = v.x - m4 - lg; o.y = v.y - m4 - lg;
        o.z = v.z - m4 - lg; o.w = v.w - m4 - lg;
        *(float4*)&lsm[(size_t)d * NCLS + c * 4] = o;
    }
}

extern "C" void kernel_launch(void* const* d_in, const int* in_sizes, int n_in,
                              void* d_out, int out_size, void* d_ws, size_t ws_size,
                              hipStream_t stream) {
    const float* x  = (const float*)d_in[0];
    const int*   ei = (const int*)d_in[1];
    const float* W1 = (const float*)d_in[2];
    const float* b1 = (const float*)d_in[3];
    const float* W2 = (const float*)d_in[4];
    const float* b2 = (const float*)d_in[5];

    const int N = N_NODES;
    const int E = in_sizes[1] / 2;
    const int* src = ei;
    const int* dst = ei + E;

    // workspace layout
    ushort_t* xws  = (ushort_t*)d_ws;                  // N*64 bf16 (pre-scaled)
    ushort_t* h    = xws + (size_t)N * HID;            // N*64 bf16
    ushort_t* hws  = h + (size_t)N * HID;              // N*64 bf16 (pre-scaled, padded)
    ushort_t* W1T  = hws + (size_t)N * HID;            // 64*512
    ushort_t* W2bt = W1T + (size_t)HID * 512;          // 48*64
    float* dinv    = (float*)(W2bt + 48 * HID);        // N
    int*   row_ptr = (int*)(dinv + N);                 // N+1
    int*   bcount  = row_ptr + (N + 1);                // 512
    int*   boff    = bcount + 512;                     // 512
    int*   bcursor = boff + 512;                       // 512
    int*   pairs   = bcursor + 512;                    // E
    int*   col     = pairs + E;                        // E

    const int NB_W = (N + 3) / 4;

    // 0. weight prep + zero bucket counts
    hipMemsetAsync(bcount, 0, 512 * sizeof(int), stream);
    prep_w1t_kernel<<<(HID * 512 + 255) / 256, 256, 0, stream>>>(W1, W1T);
    prep_w2t_kernel<<<(48 * HID + 255) / 256, 256, 0, stream>>>(W2, W2bt);

    // 1. bucketed CSR build (produces row_ptr, col, dinv)
    a1_count_kernel<<<256, 256, 0, stream>>>(dst, bcount, E);
    scan_buckets_kernel<<<1, 512, 0, stream>>>(bcount, boff, bcursor, E);
    a2_fill_kernel<<<256, 256, 0, stream>>>(src, dst, bcursor, pairs, E);
    b_fine_kernel<<<NBKT, 256, 0, stream>>>(pairs, boff, row_ptr, col, dinv, N, E);

    // 2. layer 1 GEMM (MFMA bf16, scaled by dinv, bf16 out)
    gemm1_mfma<<<(N + 127) / 128, 256, 0, stream>>>(x, W1T, dinv, xws, N);

    // 3. agg1 + relu
    agg1_kernel<<<NB_W, 256, 0, stream>>>(xws, col, row_ptr, dinv, b1, h, N);

    // 4. GEMM2 (MFMA)
    gemm2_mfma<<<(N / 16 + 3) / 4, 256, 0, stream>>>(h, W2bt, dinv, hws, N);

    // 5. agg2 + bias + log_softmax
    agg2_lsm_kernel<<<NB_W, 256, 0, stream>>>(hws, col, row_ptr, dinv, b2, (float*)d_out, N);
}

// Round 7
// 526.490 us; speedup vs baseline: 2.0643x; 1.0091x over previous
//
#include <hip/hip_runtime.h>
#include <hip/hip_bf16.h>
#include <math.h>

#define N_NODES 100000
#define F_IN    500
#define HID     64
#define NCLS    40
#define NBKT    ((N_NODES + 255) / 256)   // 391 coarse buckets of 256 nodes
#define STAGE_CAP 8192                     // LDS staging cap per bucket (mean 4096)

typedef __attribute__((ext_vector_type(8))) short short8v;
typedef __attribute__((ext_vector_type(4))) float floatx4;
typedef unsigned short ushort_t;
typedef unsigned int uint_t;

__device__ __forceinline__ float bflo(uint_t u) {
    union { uint_t i; float f; } v; v.i = u << 16; return v.f;
}
__device__ __forceinline__ float bfhi(uint_t u) {
    union { uint_t i; float f; } v; v.i = u & 0xffff0000u; return v.f;
}
__device__ __forceinline__ ushort_t f2bf(float f) {
    __hip_bfloat16 b = __float2bfloat16(f);
    return *(ushort_t*)&b;
}
__device__ __forceinline__ uint_t pack2(float a, float b) {
    return (uint_t)f2bf(a) | ((uint_t)f2bf(b) << 16);
}

// ============ CSR build: bucketed two-phase ============

__global__ __launch_bounds__(256) void a1_count_kernel(const int* __restrict__ dst,
                                                       int* __restrict__ bcount, int E) {
    __shared__ int c[NBKT];
    for (int i = threadIdx.x; i < NBKT; i += 256) c[i] = 0;
    __syncthreads();
    int chunk = (E + gridDim.x - 1) / gridDim.x;
    int lo = blockIdx.x * chunk;
    int hi = min(lo + chunk, E);
    for (int e = lo + threadIdx.x; e < hi; e += 256) atomicAdd(&c[dst[e] >> 8], 1);
    __syncthreads();
    for (int i = threadIdx.x; i < NBKT; i += 256)
        if (c[i]) atomicAdd(&bcount[i], c[i]);
}

__global__ void scan_buckets_kernel(const int* __restrict__ bcount,
                                    int* __restrict__ boff, int* __restrict__ bcursor, int E) {
    __shared__ int s[512];
    int tid = threadIdx.x;
    int v = (tid < NBKT) ? bcount[tid] : 0;
    s[tid] = v;
    __syncthreads();
    for (int off = 1; off < 512; off <<= 1) {
        int t = (tid >= off) ? s[tid - off] : 0;
        __syncthreads();
        s[tid] += t;
        __syncthreads();
    }
    if (tid < NBKT) {
        int ex = s[tid] - v;
        boff[tid] = ex;
        bcursor[tid] = ex;
    }
    if (tid == 0) boff[NBKT] = E;
}

__global__ __launch_bounds__(256) void a2_fill_kernel(const int* __restrict__ src,
                                                      const int* __restrict__ dst,
                                                      int* __restrict__ bcursor,
                                                      int* __restrict__ pairs, int E) {
    __shared__ int c[NBKT];
    __shared__ int base[NBKT];
    for (int i = threadIdx.x; i < NBKT; i += 256) c[i] = 0;
    __syncthreads();
    int chunk = (E + gridDim.x - 1) / gridDim.x;
    int lo = blockIdx.x * chunk;
    int hi = min(lo + chunk, E);
    for (int e = lo + threadIdx.x; e < hi; e += 256) atomicAdd(&c[dst[e] >> 8], 1);
    __syncthreads();
    for (int i = threadIdx.x; i < NBKT; i += 256) {
        int nn = c[i];
        base[i] = nn ? atomicAdd(&bcursor[i], nn) : 0;
    }
    __syncthreads();
    for (int i = threadIdx.x; i < NBKT; i += 256) c[i] = 0;
    __syncthreads();
    for (int e = lo + threadIdx.x; e < hi; e += 256) {
        int d = dst[e];
        int b = d >> 8;
        int p = base[b] + atomicAdd(&c[b], 1);
        pairs[p] = src[e] | ((d & 255) << 17);   // src < 2^17
    }
}

__global__ __launch_bounds__(256) void b_fine_kernel(const int* __restrict__ pairs,
                                                     const int* __restrict__ boff,
                                                     int* __restrict__ row_ptr,
                                                     int* __restrict__ col,
                                                     float* __restrict__ dinv, int n, int E) {
    __shared__ int w[STAGE_CAP];
    __shared__ int cnt[256];
    __shared__ int scn[256];
    __shared__ int cur[256];
    int b = blockIdx.x;
    int nb0 = b << 8;
    int nodes = min(256, n - nb0);
    int g0 = boff[b], g1 = boff[b + 1];
    int size = g1 - g0;
    int stage = min(size, STAGE_CAP);
    int tid = threadIdx.x;

    for (int i = tid; i < stage; i += 256) w[i] = pairs[g0 + i];
    cnt[tid] = 0;
    __syncthreads();
    for (int i = tid; i < size; i += 256) {
        int word = (i < stage) ? w[i] : pairs[g0 + i];
        atomicAdd(&cnt[word >> 17], 1);
    }
    __syncthreads();
    int v = cnt[tid];
    scn[tid] = v;
    __syncthreads();
    for (int off = 1; off < 256; off <<= 1) {
        int t = (tid >= off) ? scn[tid - off] : 0;
        __syncthreads();
        scn[tid] += t;
        __syncthreads();
    }
    int excl = scn[tid] - v;
    cur[tid] = g0 + excl;
    if (tid < nodes) {
        row_ptr[nb0 + tid] = g0 + excl;
        dinv[nb0 + tid] = rsqrtf((float)(v + 1));
    }
    if (tid == 0 && nb0 + nodes == n) row_ptr[n] = E;
    __syncthreads();
    for (int i = tid; i < size; i += 256) {
        int word = (i < stage) ? w[i] : pairs[g0 + i];
        int pos = atomicAdd(&cur[word >> 17], 1);
        col[pos] = word & 0x1FFFF;
    }
}

// ============ weight prep ============
__global__ void prep_w1t_kernel(const float* __restrict__ W1, ushort_t* __restrict__ W1T) {
    int idx = blockIdx.x * 256 + threadIdx.x;   // 64*512
    if (idx >= HID * 512) return;
    int nn = idx >> 9;
    int k  = idx & 511;
    float v = (k < F_IN) ? W1[(size_t)k * HID + nn] : 0.0f;
    W1T[idx] = f2bf(v);
}

__global__ void prep_w2t_kernel(const float* __restrict__ W2, ushort_t* __restrict__ W2bt) {
    int idx = blockIdx.x * 256 + threadIdx.x;   // 48*64
    if (idx >= 48 * HID) return;
    int nc = idx >> 6;
    int k  = idx & 63;
    float v = (nc < NCLS) ? W2[(size_t)k * NCLS + nc] : 0.0f;
    W2bt[idx] = f2bf(v);
}

// ============ GEMM1 (MFMA bf16, double-buffered): xws = (x @ W1)*dinv, bf16 ============
__global__ __launch_bounds__(256) void gemm1_mfma(const float* __restrict__ x,
                                                  const ushort_t* __restrict__ W1T,
                                                  const float* __restrict__ dinv,
                                                  ushort_t* __restrict__ xws, int n) {
    __shared__ __align__(16) ushort_t As[2][128 * 72];
    const int tid  = threadIdx.x;
    const int wave = tid >> 6;
    const int lane = tid & 63;
    const int m16  = lane & 15;
    const int q    = lane >> 4;
    const int r0   = blockIdx.x * 128;

    floatx4 acc[2][4];
#pragma unroll
    for (int i = 0; i < 2; i++)
#pragma unroll
        for (int j = 0; j < 4; j++) acc[i][j] = (floatx4){0.f, 0.f, 0.f, 0.f};

    const int kg    = tid & 15;   // k-quad (4 floats)
    const int rbase = tid >> 4;   // 0..15

    floatx4 pf[8];
    const floatx4 zero4 = (floatx4){0.f, 0.f, 0.f, 0.f};
    // prologue: prefetch tile 0 (kb=0 always < F_IN)
    {
        const int k4 = kg * 4;
#pragma unroll
        for (int rr = 0; rr < 8; rr++) {
            int gr = r0 + rbase + rr * 16;
            pf[rr] = (gr < n) ? __builtin_nontemporal_load((const floatx4*)&x[(size_t)gr * F_IN + k4])
                              : zero4;
        }
#pragma unroll
        for (int rr = 0; rr < 8; rr++) {
            int row = rbase + rr * 16;
            *(uint2*)&As[0][row * 72 + kg * 4] =
                make_uint2(pack2(pf[rr][0], pf[rr][1]), pack2(pf[rr][2], pf[rr][3]));
        }
    }
    __syncthreads();

    for (int it = 0; it < 8; it++) {
        const int cur = it & 1;
        // issue prefetch for tile it+1 (loads overlap MFMA below)
        if (it < 7) {
            const int k4 = (it + 1) * 64 + kg * 4;
            const bool kok = (k4 < F_IN);
#pragma unroll
            for (int rr = 0; rr < 8; rr++) {
                int gr = r0 + rbase + rr * 16;
                pf[rr] = (kok && gr < n)
                           ? __builtin_nontemporal_load((const floatx4*)&x[(size_t)gr * F_IN + k4])
                           : zero4;
            }
        }
        // compute tile it from As[cur]
        const int kb = it * 64;
#pragma unroll
        for (int kt = 0; kt < 2; kt++) {
            const int ko = kt * 32 + q * 8;
            short8v a0 = *(const short8v*)&As[cur][(wave * 32 + m16) * 72 + ko];
            short8v a1 = *(const short8v*)&As[cur][(wave * 32 + 16 + m16) * 72 + ko];
#pragma unroll
            for (int nt = 0; nt < 4; nt++) {
                short8v b = *(const short8v*)&W1T[(size_t)(nt * 16 + m16) * 512 + kb + ko];
                acc[0][nt] = __builtin_amdgcn_mfma_f32_16x16x32_bf16(a0, b, acc[0][nt], 0, 0, 0);
                acc[1][nt] = __builtin_amdgcn_mfma_f32_16x16x32_bf16(a1, b, acc[1][nt], 0, 0, 0);
            }
        }
        // stage tile it+1 into the other buffer
        if (it < 7) {
#pragma unroll
            for (int rr = 0; rr < 8; rr++) {
                int row = rbase + rr * 16;
                *(uint2*)&As[1 - cur][row * 72 + kg * 4] =
                    make_uint2(pack2(pf[rr][0], pf[rr][1]), pack2(pf[rr][2], pf[rr][3]));
            }
            __syncthreads();
        }
    }

#pragma unroll
    for (int mt = 0; mt < 2; mt++) {
#pragma unroll
        for (int i = 0; i < 4; i++) {
            int gr = r0 + wave * 32 + mt * 16 + q * 4 + i;
            if (gr < n) {
                float di = dinv[gr];
#pragma unroll
                for (int nt = 0; nt < 4; nt++) {
                    xws[(size_t)gr * HID + nt * 16 + m16] = f2bf(acc[mt][nt][i] * di);
                }
            }
        }
    }
}

// ============ agg1: h[d] = relu(dinv[d]*(Σ xws[s] + xws[d]) + b1), bf16 ============
// Wave per node; 32 edges in flight (8 predicated loads/lane-group slot).
__global__ __launch_bounds__(256) void agg1_kernel(const ushort_t* __restrict__ xws,
                                                   const int* __restrict__ col,
                                                   const int* __restrict__ row_ptr,
                                                   const float* __restrict__ dinv,
                                                   const float* __restrict__ b1,
                                                   ushort_t* __restrict__ h, int n) {
    int d = blockIdx.x * 4 + (threadIdx.x >> 6);
    if (d >= n) return;
    int lane = threadIdx.x & 63;
    int g = lane >> 4, c = lane & 15;
    int start = row_ptr[d], end = row_ptr[d + 1];
    uint2 selfv = *(const uint2*)&xws[(size_t)d * HID + c * 4];
    float4 acc = make_float4(0.f, 0.f, 0.f, 0.f);
    for (int j = start; j < end; j += 32) {
#pragma unroll
        for (int t = 0; t < 8; t++) {
            int e = j + t * 4 + g;
            if (e < end) {
                int s = col[e];
                uint2 v = *(const uint2*)&xws[(size_t)s * HID + c * 4];
                acc.x += bflo(v.x); acc.y += bfhi(v.x);
                acc.z += bflo(v.y); acc.w += bfhi(v.y);
            }
        }
    }
#pragma unroll
    for (int off = 16; off <= 32; off <<= 1) {
        acc.x += __shfl_xor(acc.x, off);
        acc.y += __shfl_xor(acc.y, off);
        acc.z += __shfl_xor(acc.z, off);
        acc.w += __shfl_xor(acc.w, off);
    }
    acc.x += bflo(selfv.x); acc.y += bfhi(selfv.x);
    acc.z += bflo(selfv.y); acc.w += bfhi(selfv.y);
    if (g == 0) {
        float di = dinv[d];
        float4 b = *(const float4*)&b1[c * 4];
        uint_t p0 = pack2(fmaxf(di * acc.x + b.x, 0.f), fmaxf(di * acc.y + b.y, 0.f));
        uint_t p1 = pack2(fmaxf(di * acc.z + b.z, 0.f), fmaxf(di * acc.w + b.w, 0.f));
        *(uint2*)&h[(size_t)d * HID + c * 4] = make_uint2(p0, p1);
    }
}

// ============ GEMM2 (MFMA bf16): hws = (h @ W2)*dinv, padded to 64 cols ============
__global__ __launch_bounds__(256) void gemm2_mfma(const ushort_t* __restrict__ h,
                                                  const ushort_t* __restrict__ W2bt,
                                                  const float* __restrict__ dinv,
                                                  ushort_t* __restrict__ hws, int n) {
    int wave = threadIdx.x >> 6, lane = threadIdx.x & 63;
    int m16 = lane & 15, q = lane >> 4;
    int r0 = (blockIdx.x * 4 + wave) * 16;
    if (r0 >= n) return;
    floatx4 acc[3];
#pragma unroll
    for (int nt = 0; nt < 3; nt++) acc[nt] = (floatx4){0.f, 0.f, 0.f, 0.f};
#pragma unroll
    for (int kt = 0; kt < 2; kt++) {
        short8v a = *(const short8v*)&h[(size_t)(r0 + m16) * HID + kt * 32 + q * 8];
#pragma unroll
        for (int nt = 0; nt < 3; nt++) {
            short8v b = *(const short8v*)&W2bt[(size_t)(nt * 16 + m16) * HID + kt * 32 + q * 8];
            acc[nt] = __builtin_amdgcn_mfma_f32_16x16x32_bf16(a, b, acc[nt], 0, 0, 0);
        }
    }
#pragma unroll
    for (int i = 0; i < 4; i++) {
        int gr = r0 + q * 4 + i;
        float di = dinv[gr];
#pragma unroll
        for (int nt = 0; nt < 3; nt++) {
            int cc = nt * 16 + m16;
            hws[(size_t)gr * HID + cc] = (cc < NCLS) ? f2bf(acc[nt][i] * di) : (ushort_t)0;
        }
        hws[(size_t)gr * HID + 48 + m16] = 0;
    }
}

// ============ agg2 + bias + log_softmax ============
__global__ __launch_bounds__(256) void agg2_lsm_kernel(const ushort_t* __restrict__ hws,
                                                       const int* __restrict__ col,
                                                       const int* __restrict__ row_ptr,
                                                       const float* __restrict__ dinv,
                                                       const float* __restrict__ b2,
                                                       float* __restrict__ out, int n) {
    int d = blockIdx.x * 4 + (threadIdx.x >> 6);
    if (d >= n) return;
    int lane = threadIdx.x & 63;
    int g = lane >> 4, c = lane & 15;
    int start = row_ptr[d], end = row_ptr[d + 1];
    uint2 selfv = *(const uint2*)&hws[(size_t)d * HID + c * 4];
    float4 acc = make_float4(0.f, 0.f, 0.f, 0.f);
    for (int j = start; j < end; j += 32) {
#pragma unroll
        for (int t = 0; t < 8; t++) {
            int e = j + t * 4 + g;
            if (e < end) {
                int s = col[e];
                uint2 v = *(const uint2*)&hws[(size_t)s * HID + c * 4];
                acc.x += bflo(v.x); acc.y += bfhi(v.x);
                acc.z += bflo(v.y); acc.w += bfhi(v.y);
            }
        }
    }
#pragma unroll
    for (int off = 16; off <= 32; off <<= 1) {
        acc.x += __shfl_xor(acc.x, off);
        acc.y += __shfl_xor(acc.y, off);
        acc.z += __shfl_xor(acc.z, off);
        acc.w += __shfl_xor(acc.w, off);
    }
    acc.x += bflo(selfv.x); acc.y += bfhi(selfv.x);
    acc.z += bflo(selfv.y); acc.w += bfhi(selfv.y);

    float di = dinv[d];
    bool act = (c < 10);
    float4 b = make_float4(0.f, 0.f, 0.f, 0.f);
    if (act) b = *(const float4*)&b2[c * 4];
    float4 v;
    v.x = di * acc.x + b.x;
    v.y = di * acc.y + b.y;
    v.z = di * acc.z + b.z;
    v.w = di * acc.w + b.w;

    float m4 = act ? fmaxf(fmaxf(v.x, v.y), fmaxf(v.z, v.w)) : -INFINITY;
#pragma unroll
    for (int off = 1; off < 16; off <<= 1) m4 = fmaxf(m4, __shfl_xor(m4, off));
    float s4 = act ? (__expf(v.x - m4) + __expf(v.y - m4) + __expf(v.z - m4) + __expf(v.w - m4)) : 0.f;
#pragma unroll
    for (int off = 1; off < 16; off <<= 1) s4 += __shfl_xor(s4, off);

    if (act && g == 0) {
        float lg = __logf(s4);
        float* lsm    = out;
        float* logits = out + (size_t)N_NODES * NCLS;
        *(float4*)&logits[(size_t)d * NCLS + c * 4] = v;
        float4 o;
        o.x = v.x - m4 - lg; o.y = v.y - m4 - lg;
        o.z = v.z - m4 - lg; o.w = v.w - m4 - lg;
        *(float4*)&lsm[(size_t)d * NCLS + c * 4] = o;
    }
}

extern "C" void kernel_launch(void* const* d_in, const int* in_sizes, int n_in,
                              void* d_out, int out_size, void* d_ws, size_t ws_size,
                              hipStream_t stream) {
    const float* x  = (const float*)d_in[0];
    const int*   ei = (const int*)d_in[1];
    const float* W1 = (const float*)d_in[2];
    const float* b1 = (const float*)d_in[3];
    const float* W2 = (const float*)d_in[4];
    const float* b2 = (const float*)d_in[5];

    const int N = N_NODES;
    const int E = in_sizes[1] / 2;
    const int* src = ei;
    const int* dst = ei + E;

    // workspace layout
    ushort_t* xws  = (ushort_t*)d_ws;                  // N*64 bf16 (pre-scaled)
    ushort_t* h    = xws + (size_t)N * HID;            // N*64 bf16
    ushort_t* hws  = h + (size_t)N * HID;              // N*64 bf16 (pre-scaled, padded)
    ushort_t* W1T  = hws + (size_t)N * HID;            // 64*512
    ushort_t* W2bt = W1T + (size_t)HID * 512;          // 48*64
    float* dinv    = (float*)(W2bt + 48 * HID);        // N
    int*   row_ptr = (int*)(dinv + N);                 // N+1
    int*   bcount  = row_ptr + (N + 1);                // 512
    int*   boff    = bcount + 512;                     // 512
    int*   bcursor = boff + 512;                       // 512
    int*   pairs   = bcursor + 512;                    // E
    int*   col     = pairs + E;                        // E

    const int NB_W = (N + 3) / 4;

    // 0. weight prep + zero bucket counts
    (void)hipMemsetAsync(bcount, 0, 512 * sizeof(int), stream);
    prep_w1t_kernel<<<(HID * 512 + 255) / 256, 256, 0, stream>>>(W1, W1T);
    prep_w2t_kernel<<<(48 * HID + 255) / 256, 256, 0, stream>>>(W2, W2bt);

    // 1. bucketed CSR build (produces row_ptr, col, dinv)
    a1_count_kernel<<<256, 256, 0, stream>>>(dst, bcount, E);
    scan_buckets_kernel<<<1, 512, 0, stream>>>(bcount, boff, bcursor, E);
    a2_fill_kernel<<<256, 256, 0, stream>>>(src, dst, bcursor, pairs, E);
    b_fine_kernel<<<NBKT, 256, 0, stream>>>(pairs, boff, row_ptr, col, dinv, N, E);

    // 2. layer 1 GEMM (MFMA bf16, double-buffered, scaled by dinv, bf16 out)
    gemm1_mfma<<<(N + 127) / 128, 256, 0, stream>>>(x, W1T, dinv, xws, N);

    // 3. agg1 + relu
    agg1_kernel<<<NB_W, 256, 0, stream>>>(xws, col, row_ptr, dinv, b1, h, N);

    // 4. GEMM2 (MFMA)
    gemm2_mfma<<<(N / 16 + 3) / 4, 256, 0, stream>>>(h, W2bt, dinv, hws, N);

    // 5. agg2 + bias + log_softmax
    agg2_lsm_kernel<<<NB_W, 256, 0, stream>>>(hws, col, row_ptr, dinv, b2, (float*)d_out, N);
}